// Round 7
// baseline (709.976 us; speedup 1.0000x reference)
//
#include <hip/hip_runtime.h>
#include <cstdint>
#include <cstddef>

typedef __bf16 bf16x8 __attribute__((ext_vector_type(8)));
typedef __bf16 bf16x4 __attribute__((ext_vector_type(4)));
typedef float  f32x4  __attribute__((ext_vector_type(4)));

#define MFMA16(a,b,c) __builtin_amdgcn_mfma_f32_16x16x32_bf16((a),(b),(c),0,0,0)

// LDS-only barrier: per-step double-buffer handoff needs lgkmcnt(0) only.
// Global stores are drained explicitly at publish points (BAR_FULL).
#define BAR_LGKM() __asm__ volatile("s_waitcnt lgkmcnt(0)\n\ts_barrier" ::: "memory")
#define BAR_FULL() __asm__ volatile("s_waitcnt vmcnt(0) lgkmcnt(0)\n\ts_barrier" ::: "memory")

// Problem: B=256, T=512, D=H=128, 3H=384. x/out batch stride = 65536 elems.
// One 32-block kernel: blocks 0..15 = layer 0 (producer), 16..31 = layer 1
// (consumer, lagged 8..15 steps). h0 crosses XCDs via nt stores/loads +
// per-pair 64B-padded agent-scope progress flags, published every 8th step.
//
// TRANSPOSED orientation: C = Wstack^T(A, M=gates) x [x|h]^T(B, N=batch).
// C layout: col(lane&15) = batch, row(quad*4+reg) = 4 CONSECUTIVE gate-cols
// -> h LDS write = one ds_write_b64, global h/out store = one dwordx4.

// ---------------------------------------------------------------------------
// prep_frags: stacked-weight frags, K=256 ([W(128);U(128)]), + flag init.
// Element offset = ((ct*8+kt)*64 + lane)*8 + j  holds
// Wstack[kt*32 + (lane>>4)*8 + j][ct*16 + (lane&15)]  (ct 0..23, kt 0..7).
// Read as A-operand: lane holds A[m = ct*16+l15][k = kt*32+quad*8+j]. ✓
// ---------------------------------------------------------------------------
__global__ void prep_frags(const float* __restrict__ W0, const float* __restrict__ U0,
                           const float* __restrict__ W1, const float* __restrict__ U1,
                           __bf16* __restrict__ frags, int* __restrict__ flags)
{
    if (blockIdx.x == 0 && threadIdx.x < 16) flags[threadIdx.x * 16] = 0;
    int id = blockIdx.x * 512 + threadIdx.x;      // 0..24575
    int layer = id / 12288;
    int r     = id % 12288;                       // (ct*8+kt)*64 + lane
    int lane = r & 63;
    int ctkt = r >> 6;                            // 0..191
    int kt = ctkt & 7;
    int ct = ctkt >> 3;
    const float* Wsrc = layer ? W1 : W0;
    const float* Usrc = layer ? U1 : U0;
    int n  = ct * 16 + (lane & 15);
    int k0 = kt * 32 + (lane >> 4) * 8;           // never straddles 128
    const float* src = (k0 < 128) ? (Wsrc + (size_t)k0 * 384)
                                  : (Usrc + (size_t)(k0 - 128) * 384);
    __bf16* dst = frags + (size_t)layer * 98304 + (size_t)r * 8;
#pragma unroll
    for (int j = 0; j < 8; j++)
        dst[j] = (__bf16)src[(size_t)j * 384 + n];
}

// ---------------------------------------------------------------------------
// gru_pipe: both GRU layers, pipelined across block pairs.
// Per block: 16 batch rows, 512 threads (8 waves, 2/SIMD). Wave w owns gate
// cols [16w,16w+16) via A-tiles ct = 8g + w. Dynamic B = [x_t | h_{t-1}] bf16,
// batch-major LDS (stride 264), double-buffered, ONE lgkm barrier/step.
// acc: z(K256), r(K256), xh(kt0-3), rec_h(kt4-7) — reset_after applies r to
// the recurrent part only. Lane owns batch l15, cols c0..c0+3 (c0=16w+4*quad).
// h0 may alias out (small-ws fallback): consumer reads slot t+2 strictly
// before overwriting slot t. No __restrict__ on x/h0/out.
// ---------------------------------------------------------------------------
__global__ __launch_bounds__(512, 2) void gru_pipe(
    const float* x, const __bf16* __restrict__ frags,
    const float* __restrict__ b0, const float* __restrict__ b1,
    float* h0, float* out, int* flags)
{
    __shared__ __align__(16) __bf16 ab[2][16 * 264];

    const int tid = threadIdx.x;
    const int wave = tid >> 6, lane = tid & 63;
    const int l15 = lane & 15, quad = lane >> 4;
    const int pair  = blockIdx.x & 15;
    const int layer = blockIdx.x >> 4;
    const int B0 = pair * 16;
    int* const flagp = flags + pair * 16;          // one 64B line per pair

    const __bf16* Bf  = frags + (size_t)layer * 98304;
    const float* bias = layer ? b1 : b0;
    const float* xin  = layer ? h0 : x;
    float*       hout = layer ? out : h0;

    // persistent weight A-frags: 3 gates x 8 kt = 24 frags
    bf16x8 wfr[3][8];
#pragma unroll
    for (int g = 0; g < 3; g++) {
        int ct = 8 * g + wave;
#pragma unroll
        for (int kt = 0; kt < 8; kt++)
            wfr[g][kt] = *(const bf16x8*)(Bf + (size_t)((ct * 8 + kt) * 64 + lane) * 8);
    }

    const int c0 = wave * 16 + quad * 4;           // 4 gate-cols owned by lane
    const f32x4 bz4  = *(const f32x4*)(bias + c0)       + *(const f32x4*)(bias + 384 + c0);
    const f32x4 br4  = *(const f32x4*)(bias + 128 + c0) + *(const f32x4*)(bias + 512 + c0);
    const f32x4 bih4 = *(const f32x4*)(bias + 256 + c0);
    const f32x4 brh4 = *(const f32x4*)(bias + 640 + c0);

    // staging map: 512 threads cover 16 rows x 128 cols (4 floats each)
    const int srow = tid >> 5;
    const int c4   = (tid & 31) * 4;
    const float* px = xin + (size_t)(B0 + srow) * 65536 + c4;
    const int sidx = srow * 264 + c4;

    // output: lane owns batch B0+l15, cols c0..c0+3 (one float4 per step)
    float* const po = hout + (size_t)(B0 + l15) * 65536 + c0;

    int known = 0;
    if (layer) {
        known = __hip_atomic_load(flagp, __ATOMIC_RELAXED, __HIP_MEMORY_SCOPE_AGENT);
        while (known < 2) {
            __builtin_amdgcn_s_sleep(4);
            known = __hip_atomic_load(flagp, __ATOMIC_RELAXED, __HIP_MEMORY_SCOPE_AGENT);
        }
    }

    // ---- prologue: stage step-0 input, zero h-part, preload step 1 ----
    f32x4 vc = layer ? __builtin_nontemporal_load((const f32x4*)px)
                     : *(const f32x4*)px;
    {
        bf16x4 hv;
        hv.x = (__bf16)vc[0]; hv.y = (__bf16)vc[1];
        hv.z = (__bf16)vc[2]; hv.w = (__bf16)vc[3];
        *(bf16x4*)&ab[0][sidx] = hv;
    }
    if (tid < 256) {
        int row = tid >> 4, seg = tid & 15;
        *(uint4*)&ab[0][row * 264 + 128 + seg * 8] = make_uint4(0, 0, 0, 0);
    }
    __syncthreads();
    vc = layer ? __builtin_nontemporal_load((const f32x4*)(px + 128))
               : *(const f32x4*)(px + 128);

    f32x4 hold = {0.f, 0.f, 0.f, 0.f};
    const int abase = l15 * 264 + quad * 8;
    const int hwoff = l15 * 264 + 128 + c0;        // b64 h-write address

    for (int t = 0; t < 512; t++) {
        const int cur = t & 1, nxt = cur ^ 1;

        if (layer) {                                // gate the t+2 prefetch
            int need = t + 3; if (need > 512) need = 512;
            if (known < need) {
                known = __hip_atomic_load(flagp, __ATOMIC_RELAXED, __HIP_MEMORY_SCOPE_AGENT);
                while (known < need) {
                    __builtin_amdgcn_s_sleep(4);
                    known = __hip_atomic_load(flagp, __ATOMIC_RELAXED, __HIP_MEMORY_SCOPE_AGENT);
                }
            }
        }
        const int t2 = (t < 510) ? (t + 2) : 511;
        f32x4 vn = layer
            ? __builtin_nontemporal_load((const f32x4*)(px + (size_t)t2 * 128))
            : *(const f32x4*)(px + (size_t)t2 * 128);

        // dynamic B-frags: 8 K-slabs (x: kt 0..3, h: kt 4..7)
        bf16x8 A[8];
#pragma unroll
        for (int kt = 0; kt < 8; kt++)
            A[kt] = *(const bf16x8*)&ab[cur][abase + kt * 32];

        f32x4 acc[4] = {{0,0,0,0},{0,0,0,0},{0,0,0,0},{0,0,0,0}};
#pragma unroll
        for (int kt = 0; kt < 8; kt++) {
            acc[0] = MFMA16(wfr[0][kt], A[kt], acc[0]);          // z (merged)
            acc[1] = MFMA16(wfr[1][kt], A[kt], acc[1]);          // r (merged)
            acc[(kt < 4) ? 2 : 3] = MFMA16(wfr[2][kt], A[kt], acc[(kt < 4) ? 2 : 3]);
        }

        f32x4 hnew;
#pragma unroll
        for (int r = 0; r < 4; r++) {
            float zp = acc[0][r] + bz4[r];
            float rp = acc[1][r] + br4[r];
            float z  = __builtin_amdgcn_rcpf(1.f + __expf(-zp));
            float rg = __builtin_amdgcn_rcpf(1.f + __expf(-rp));
            float hp = (acc[2][r] + bih4[r]) + rg * (acc[3][r] + brh4[r]);
            float e2 = __expf(2.f * hp);
            float th = 1.f - 2.f * __builtin_amdgcn_rcpf(e2 + 1.f);
            hnew[r] = th + z * (hold[r] - th);
            hold[r] = hnew[r];
        }

        // stage step t+1 input (vc from previous prefetch)
        {
            bf16x4 hv;
            hv.x = (__bf16)vc[0]; hv.y = (__bf16)vc[1];
            hv.z = (__bf16)vc[2]; hv.w = (__bf16)vc[3];
            *(bf16x4*)&ab[nxt][sidx] = hv;
        }
        // h_t -> LDS h-part: 4 consecutive bf16 = one b64 write
        {
            bf16x4 hv;
            hv.x = (__bf16)hnew[0]; hv.y = (__bf16)hnew[1];
            hv.z = (__bf16)hnew[2]; hv.w = (__bf16)hnew[3];
            *(bf16x4*)&ab[nxt][hwoff] = hv;
        }

        // barrier: lgkm-only normally; full drain + publish every 8th step
        if (layer == 0 && (t & 7) == 7) {
            BAR_FULL();                 // h0 stores of steps <= t-1 in HBM
            if (tid == 0)
                __hip_atomic_store(flagp, t, __ATOMIC_RELAXED,
                                   __HIP_MEMORY_SCOPE_AGENT);
        } else {
            BAR_LGKM();
        }

        // h_t -> global: one float4 per lane (drains during later steps)
        if (layer == 0)
            __builtin_nontemporal_store(hnew, (f32x4*)(po + (size_t)t * 128));
        else
            *(f32x4*)(po + (size_t)t * 128) = hnew;

        vc = vn;
    }

    if (layer == 0) {
        BAR_FULL();        // drain final h0 stores (incl. step 511)
        if (tid == 0)
            __hip_atomic_store(flagp, 512, __ATOMIC_RELAXED,
                               __HIP_MEMORY_SCOPE_AGENT);
    }
}

// ---------------------------------------------------------------------------
extern "C" void kernel_launch(void* const* d_in, const int* in_sizes, int n_in,
                              void* d_out, int out_size, void* d_ws, size_t ws_size,
                              hipStream_t stream)
{
    const float* x  = (const float*)d_in[0];
    const float* W0 = (const float*)d_in[1];
    const float* U0 = (const float*)d_in[2];
    const float* b0 = (const float*)d_in[3];
    const float* W1 = (const float*)d_in[4];
    const float* U1 = (const float*)d_in[5];
    const float* b1 = (const float*)d_in[6];
    float* out = (float*)d_out;

    char* ws = (char*)d_ws;
    __bf16* frags = (__bf16*)ws;                 // 2 * 98304 bf16 = 393,216 B
    int*    flags = (int*)(ws + 393216);         // 16 pairs x 64 B = 1024 B
    // h0 at ws + 448 KiB if it fits, else alias d_out (pipeline-safe: consumer
    // reads slot t+2 strictly before overwriting slot t).
    float* h0;
    const size_t need = 458752 + 67108864;
    if (ws_size >= need) h0 = (float*)(ws + 458752);
    else                 h0 = out;

    prep_frags<<<48, 512, 0, stream>>>(W0, U0, W1, U1, frags, flags);
    gru_pipe<<<32, 512, 0, stream>>>(x, frags, b0, b1, h0, out, flags);
}